// Round 8
// baseline (2355.768 us; speedup 1.0000x reference)
//
#include <hip/hip_runtime.h>
#include <math.h>

// BinaryTreeLSTM on MI355X — R11.
// vs R10 (260us, flag-barrier tail 90us — device-wide sync ~10us/level on
// 8-XCD, REJECTED twice): fuse levels via SELF-CONTAINED blocks instead.
// Rows 2i,2i+1 at level l feed exactly row i at level l+1 => a block owning
// a 16-row tile at the final level computes its own ancestors across ALL 256
// cols. Intermediate level lives in LDS only (h bf16 XOR-swizzled for MFMA
// A-reads, c f32); __syncthreads between levels; NO cross-block sync.
//  - k_fusen<2>: (2048,1024) 64 blk, (512,256) 16 blk, (128,64) 4 blk
//  - k_fusen<6>: levels 32..1 in ONE block (serial work anyway)
// Front-end = R9's proven prep1 / leaf_fused / rt2(4096).
// Dispatches: 7 (was 15).

#define MEM 256

typedef __attribute__((ext_vector_type(8))) short bf16x8;
typedef __attribute__((ext_vector_type(4))) float f32x4;

__device__ __forceinline__ float sigf(float x) { return 1.0f / (1.0f + __expf(-x)); }

__device__ __forceinline__ unsigned short f2b(float f) {
  unsigned int u = __float_as_uint(f);
  u = (u + 0x7FFFu + ((u >> 16) & 1u)) >> 16;
  return (unsigned short)u;
}

// 8 consecutive f32 -> bf16x8
__device__ __forceinline__ bf16x8 c8(const float* __restrict__ p) {
  float4 f0 = *(const float4*)(p);
  float4 f1 = *(const float4*)(p + 4);
  bf16x8 r;
  r[0] = (short)f2b(f0.x); r[1] = (short)f2b(f0.y);
  r[2] = (short)f2b(f0.z); r[3] = (short)f2b(f0.w);
  r[4] = (short)f2b(f1.x); r[5] = (short)f2b(f1.y);
  r[6] = (short)f2b(f1.z); r[7] = (short)f2b(f1.w);
  return r;
}

// 8 consecutive k from a 300-long f32 row, zero-padded past 300
__device__ __forceinline__ bf16x8 g8(const float* __restrict__ rp, int k0) {
  if (k0 + 8 <= 300) return c8(rp + k0);
  bf16x8 r;
#pragma unroll
  for (int j = 0; j < 8; j++) {
    int k = k0 + j;
    r[j] = (k < 300) ? (short)f2b(rp[k]) : (short)0;
  }
  return r;
}

// ---- Prep1: eb (embs->bf16) | Wxf shuffle ----
#define NB_EB 1280   // 8192*320/2048
#define NB_WXF 120   // 480*512/2048
__global__ __launch_bounds__(256) void k_prep1(
    const float* __restrict__ embs, const float* __restrict__ Wx,
    unsigned short* __restrict__ eb, unsigned short* __restrict__ Wxf) {
  int b = blockIdx.x, tid = threadIdx.x;
  if (b < NB_EB) {
    int idx8 = (b * 256 + tid) * 8;       // 8192*320
    int row = idx8 / 320;
    int k0 = idx8 - row * 320;
    *(bf16x8*)(eb + idx8) = g8(embs + row * 300, k0);
  } else {
    int idx8 = ((b - NB_EB) * 256 + tid) * 8;  // 480*512
    int f = idx8 >> 9, rr = idx8 & 511;
    int lane = rr >> 3;
    int gate = f % 3, t = f / 3;
    int grp = t & 15, kc = t >> 4;
    int k0 = kc * 32 + ((lane >> 4) << 3);
    const int gmap[3] = {0, 1, 3};
    int n = gmap[gate] * 256 + (grp << 4) + (lane & 15);
    *(bf16x8*)(Wxf + idx8) = g8(Wx + n * 300, k0);
  }
}

// ---- Leaf (0..1023) | Wcf shuffle (1024..1343) | bias5 (1344..1348) ----
#define NB_LEAF 1024
#define NB_WCF 320   // 1280*512/2048
__global__ __launch_bounds__(256) void k_leaf_fused(
    const unsigned short* __restrict__ eb, const unsigned short* __restrict__ Wxf,
    const float* __restrict__ bx, const float* __restrict__ Wx,
    const float* __restrict__ Wl, const float* __restrict__ Wr,
    const float* __restrict__ emb_last,
    unsigned short* __restrict__ Wcf, float* __restrict__ bias5,
    float* __restrict__ cO, unsigned short* __restrict__ hO) {
  int b = blockIdx.x, tid = threadIdx.x;
  if (b < NB_LEAF) {
    int slice = b & 7, rest = b >> 3;
    int rowblock = slice * 8 + (rest & 7);
    int grp = rest >> 3;
    int lane = tid & 63, wave = tid >> 6;
    int tb = (rowblock * 4 + wave) * 2;
    int m = lane & 15, quad = lane >> 4;

    f32x4 acc[2][3];
#pragma unroll
    for (int rt = 0; rt < 2; rt++)
#pragma unroll
      for (int g = 0; g < 3; g++) acc[rt][g] = (f32x4){0.f, 0.f, 0.f, 0.f};

    const unsigned short* ar0 = eb + (tb * 16 + m) * 320 + quad * 8;
    const unsigned short* ar1 = eb + ((tb + 1) * 16 + m) * 320 + quad * 8;
#pragma unroll
    for (int kc = 0; kc < 10; kc++) {
      const unsigned short* bp = Wxf + ((kc * 16 + grp) * 3) * 512 + lane * 8;
      bf16x8 b0 = *(const bf16x8*)(bp);
      bf16x8 b1 = *(const bf16x8*)(bp + 512);
      bf16x8 b2 = *(const bf16x8*)(bp + 1024);
      bf16x8 a0 = *(const bf16x8*)(ar0 + kc * 32);
      bf16x8 a1 = *(const bf16x8*)(ar1 + kc * 32);
      acc[0][0] = __builtin_amdgcn_mfma_f32_16x16x32_bf16(a0, b0, acc[0][0], 0, 0, 0);
      acc[0][1] = __builtin_amdgcn_mfma_f32_16x16x32_bf16(a0, b1, acc[0][1], 0, 0, 0);
      acc[0][2] = __builtin_amdgcn_mfma_f32_16x16x32_bf16(a0, b2, acc[0][2], 0, 0, 0);
      acc[1][0] = __builtin_amdgcn_mfma_f32_16x16x32_bf16(a1, b0, acc[1][0], 0, 0, 0);
      acc[1][1] = __builtin_amdgcn_mfma_f32_16x16x32_bf16(a1, b1, acc[1][1], 0, 0, 0);
      acc[1][2] = __builtin_amdgcn_mfma_f32_16x16x32_bf16(a1, b2, acc[1][2], 0, 0, 0);
    }
    int col = grp * 16 + m;
    float b0 = bx[col], b1 = bx[256 + col], b3 = bx[768 + col];
#pragma unroll
    for (int rt = 0; rt < 2; rt++) {
#pragma unroll
      for (int reg = 0; reg < 4; reg++) {
        int row = (tb + rt) * 16 + quad * 4 + reg;
        float u = tanhf(acc[rt][0][reg] + b0);
        float ig = sigf(acc[rt][1][reg] + b1);
        float o = sigf(acc[rt][2][reg] + b3);
        float c = ig * u;
        cO[row * MEM + col] = c;
        hO[row * MEM + col] = f2b(o * tanhf(c));
      }
    }
  } else if (b < NB_LEAF + NB_WCF) {
    int idx8 = ((b - NB_LEAF) * 256 + tid) * 8;  // 1280*512
    int f = idx8 >> 9, rr = idx8 & 511;
    int lane = rr >> 3;
    int gate = f % 5, t = f / 5;
    int grp = t & 15, kc = t >> 4;
    int k0 = kc * 32 + ((lane >> 4) << 3);
    int n = gate * 256 + (grp << 4) + (lane & 15);
    const float* src = (k0 < 256) ? (Wl + n * 256 + k0) : (Wr + n * 256 + (k0 - 256));
    *(bf16x8*)(Wcf + idx8) = c8(src);
  } else {
    int g = b - (NB_LEAF + NB_WCF);  // 0..4
    __shared__ float er[300];
    for (int k = tid; k < 300; k += 256) er[k] = emb_last[k];
    __syncthreads();
    const int map[5] = {0, 1, 2, 2, 3};
    int wrow = map[g] * 256 + tid;
    const float* w = Wx + wrow * 300;
    float s = bx[wrow];
    for (int k = 0; k < 300; k++) s += er[k] * w[k];
    bias5[g * 256 + tid] = s;
  }
}

// ---- Compose RT=2 (B=4096 only): 1-D grid(512), row-affine slices ----
__global__ __launch_bounds__(256) void k_compose_rt2(
    const unsigned short* __restrict__ hprev, const float* __restrict__ cprev,
    const unsigned short* __restrict__ Wcf, const float* __restrict__ bias5,
    float* __restrict__ cO, unsigned short* __restrict__ hO, int B) {
  int bid = blockIdx.x;
  int slice = bid & 7;
  int rest = bid >> 3;
  int rowblock = slice * 4 + (rest & 3);
  int grp = rest >> 2;
  int lane = threadIdx.x & 63;
  int wave = threadIdx.x >> 6;
  int tb = (rowblock * 4 + wave) * 2;
  int m = lane & 15, quad = lane >> 4;

  f32x4 acc[2][5];
  const unsigned short* ar[2];
#pragma unroll
  for (int rt = 0; rt < 2; rt++) {
    int ra = (tb + rt) * 16 + m;
    ar[rt] = hprev + ra * 512 + quad * 8;
#pragma unroll
    for (int g = 0; g < 5; g++) acc[rt][g] = (f32x4){0.f, 0.f, 0.f, 0.f};
  }

#pragma unroll
  for (int kc = 0; kc < 16; kc++) {
    const unsigned short* bp = Wcf + ((kc * 16 + grp) * 5) * 512 + lane * 8;
    bf16x8 b0 = *(const bf16x8*)(bp);
    bf16x8 b1 = *(const bf16x8*)(bp + 512);
    bf16x8 b2 = *(const bf16x8*)(bp + 1024);
    bf16x8 b3 = *(const bf16x8*)(bp + 1536);
    bf16x8 b4 = *(const bf16x8*)(bp + 2048);
#pragma unroll
    for (int rt = 0; rt < 2; rt++) {
      bf16x8 a = *(const bf16x8*)(ar[rt] + kc * 32);
      acc[rt][0] = __builtin_amdgcn_mfma_f32_16x16x32_bf16(a, b0, acc[rt][0], 0, 0, 0);
      acc[rt][1] = __builtin_amdgcn_mfma_f32_16x16x32_bf16(a, b1, acc[rt][1], 0, 0, 0);
      acc[rt][2] = __builtin_amdgcn_mfma_f32_16x16x32_bf16(a, b2, acc[rt][2], 0, 0, 0);
      acc[rt][3] = __builtin_amdgcn_mfma_f32_16x16x32_bf16(a, b3, acc[rt][3], 0, 0, 0);
      acc[rt][4] = __builtin_amdgcn_mfma_f32_16x16x32_bf16(a, b4, acc[rt][4], 0, 0, 0);
    }
  }
  int col = grp * 16 + m;
  float b0 = bias5[col], b1 = bias5[256 + col], b2 = bias5[512 + col];
  float b3 = bias5[768 + col], b4 = bias5[1024 + col];
#pragma unroll
  for (int rt = 0; rt < 2; rt++) {
#pragma unroll
    for (int reg = 0; reg < 4; reg++) {
      int row = (tb + rt) * 16 + quad * 4 + reg;
      float u = tanhf(acc[rt][0][reg] + b0);
      float ig = sigf(acc[rt][1][reg] + b1);
      float lf = sigf(acc[rt][2][reg] + b2);
      float rf = sigf(acc[rt][3][reg] + b3);
      float o = sigf(acc[rt][4][reg] + b4);
      float lc = cprev[(2 * row) * MEM + col];
      float rc = cprev[(2 * row + 1) * MEM + col];
      float c = ig * u + lf * lc + rf * rc;
      cO[row * MEM + col] = c;
      hO[row * MEM + col] = f2b(o * tanhf(c));
    }
  }
}

// ---- Self-contained multi-level compose ----
// Block t owns the final-level tile [t*16, t*16+16) and computes all its
// ancestor rows at every intermediate level across ALL 256 columns.
// Level j (j=0..NLEV-1): output rows B_j = B_in >> (j+1); per block R = B_j/Nb.
// Intermediate (c,h) in LDS: h bf16 row-major [row][256] with byte XOR-swizzle
// (byte ^= ((byte>>10)&7)<<4) so the MFMA A-read (vrow stride 1024B) spreads
// banks; c plain f32 [row][256]. One __syncthreads per level. Wave handles
// grps 4w..4w+3 x 5 gates (self-contained epilogue, no cross-wave exchange).
template <int NLEV>
__global__ __launch_bounds__(256) void k_fusen(
    const unsigned short* __restrict__ h_in,  // B_in x 256 bf16
    const float* __restrict__ c_in,           // B_in x 256 f32
    const unsigned short* __restrict__ Wcf, const float* __restrict__ bias5,
    float* __restrict__ cO, unsigned short* __restrict__ hO,
    float* __restrict__ outv, int B_in) {
  constexpr int NBUF = (NLEV > 2) ? 2 : 1;
  __shared__ __align__(16) unsigned short h_s[NBUF][32 * 256];  // 16KB each
  __shared__ __align__(16) float c_s[NBUF][32 * 256];           // 32KB each
  int t = blockIdx.x, Nb = gridDim.x;
  int tid = threadIdx.x;
  int lane = tid & 63, wave = tid >> 6;
  int m = lane & 15, quad = lane >> 4;

  float bs[4][5];
#pragma unroll
  for (int gi = 0; gi < 4; gi++)
#pragma unroll
    for (int q = 0; q < 5; q++)
      bs[gi][q] = bias5[q * 256 + (wave * 4 + gi) * 16 + m];

  const bf16x8 zz = {0, 0, 0, 0, 0, 0, 0, 0};
  int Bj = B_in;
  for (int j = 0; j < NLEV; j++) {
    Bj >>= 1;                       // output rows of level j
    int R = Bj / Nb;                // rows this block computes
    if (R == 0) R = Bj;             // (Nb=1 small levels)
    int nrt = (R + 15) >> 4;
    int rbuf = j & (NBUF - 1);
    int wbuf = (j + 1) & (NBUF - 1);

    for (int rt = 0; rt < nrt; rt++) {
      f32x4 acc[4][5];
#pragma unroll
      for (int gi = 0; gi < 4; gi++)
#pragma unroll
        for (int q = 0; q < 5; q++) acc[gi][q] = (f32x4){0.f, 0.f, 0.f, 0.f};
      int vrow = rt * 16 + m;       // A view-row == output row
      bool okA = vrow < R;
#pragma unroll
      for (int kc = 0; kc < 16; kc++) {
        bf16x8 av;
        if (j == 0) {
          const unsigned short* ap =
              h_in + (size_t)(t * R + vrow) * 512 + kc * 32 + quad * 8;
          av = okA ? *(const bf16x8*)ap : zz;
        } else {
          int byte = vrow * 1024 + kc * 64 + quad * 16;
          byte ^= ((byte >> 10) & 7) << 4;
          av = okA ? *(const bf16x8*)((const char*)h_s[rbuf] + byte) : zz;
        }
#pragma unroll
        for (int gi = 0; gi < 4; gi++) {
          const unsigned short* wp =
              Wcf + ((kc * 16 + (wave * 4 + gi)) * 5) * 512 + lane * 8;
          acc[gi][0] = __builtin_amdgcn_mfma_f32_16x16x32_bf16(av, *(const bf16x8*)(wp), acc[gi][0], 0, 0, 0);
          acc[gi][1] = __builtin_amdgcn_mfma_f32_16x16x32_bf16(av, *(const bf16x8*)(wp + 512), acc[gi][1], 0, 0, 0);
          acc[gi][2] = __builtin_amdgcn_mfma_f32_16x16x32_bf16(av, *(const bf16x8*)(wp + 1024), acc[gi][2], 0, 0, 0);
          acc[gi][3] = __builtin_amdgcn_mfma_f32_16x16x32_bf16(av, *(const bf16x8*)(wp + 1536), acc[gi][3], 0, 0, 0);
          acc[gi][4] = __builtin_amdgcn_mfma_f32_16x16x32_bf16(av, *(const bf16x8*)(wp + 2048), acc[gi][4], 0, 0, 0);
        }
      }
      // epilogue for this row-tile
#pragma unroll
      for (int gi = 0; gi < 4; gi++) {
        int col = (wave * 4 + gi) * 16 + m;
#pragma unroll
        for (int reg = 0; reg < 4; reg++) {
          int lrow = rt * 16 + quad * 4 + reg;
          if (lrow >= R) continue;
          float u = tanhf(acc[gi][0][reg] + bs[gi][0]);
          float ig = sigf(acc[gi][1][reg] + bs[gi][1]);
          float lf = sigf(acc[gi][2][reg] + bs[gi][2]);
          float rf = sigf(acc[gi][3][reg] + bs[gi][3]);
          float o = sigf(acc[gi][4][reg] + bs[gi][4]);
          float lc, rc;
          if (j == 0) {
            size_t g0 = (size_t)(t * R + lrow);
            lc = c_in[(2 * g0) * 256 + col];
            rc = c_in[(2 * g0 + 1) * 256 + col];
          } else {
            lc = c_s[rbuf][(2 * lrow) * 256 + col];
            rc = c_s[rbuf][(2 * lrow + 1) * 256 + col];
          }
          float c = ig * u + lf * lc + rf * rc;
          float h = o * tanhf(c);
          if (j == NLEV - 1) {
            if (outv) {
              outv[col] = c;
              outv[256 + col] = h;
            } else {
              int go = t * R + lrow;
              cO[go * 256 + col] = c;
              hO[go * 256 + col] = f2b(h);
            }
          } else {
            int byteh = lrow * 512 + col * 2;
            byteh ^= ((byteh >> 10) & 7) << 4;
            *(unsigned short*)((char*)h_s[wbuf] + byteh) = f2b(h);
            c_s[wbuf][lrow * 256 + col] = c;
          }
        }
      }
    }
    if (j < NLEV - 1) __syncthreads();
  }
}

extern "C" void kernel_launch(void* const* d_in, const int* in_sizes, int n_in,
                              void* d_out, int out_size, void* d_ws, size_t ws_size,
                              hipStream_t stream) {
  const float* embs = (const float*)d_in[0];
  const float* Wx = (const float*)d_in[1];
  const float* bx = (const float*)d_in[2];
  const float* Wl = (const float*)d_in[3];
  const float* Wr = (const float*)d_in[4];
  const float* emb_table = (const float*)d_in[5];
  float* out = (float*)d_out;

  // Workspace layout (~25 MB)
  float* ws = (float*)d_ws;
  float* cA = ws;                               // 8192*256 f32
  float* cB = cA + 8192 * 256;                  // 4096*256 f32
  float* bias5 = cB + 4096 * 256;               // 1280 f32
  unsigned short* hA = (unsigned short*)(bias5 + 1280);  // 8192*256 bf16
  unsigned short* hB = hA + 8192 * 256;                  // 4096*256 bf16
  unsigned short* Wcf = hB + 4096 * 256;                 // 1280*512
  unsigned short* Wxf = Wcf + 1280 * 512;                // 480*512
  unsigned short* eb = Wxf + 480 * 512;                  // 8192*320

  // 1) Prep1: eb + Wxf (1400 blocks)
  k_prep1<<<NB_EB + NB_WXF, 256, 0, stream>>>(embs, Wx, eb, Wxf);

  // 2) Leaf (+ Wcf shuffle + bias5 overlapped) -> cA, hA (8192 rows)
  k_leaf_fused<<<NB_LEAF + NB_WCF + 5, 256, 0, stream>>>(
      eb, Wxf, bx, Wx, Wl, Wr, emb_table + (in_sizes[5] - 300),
      Wcf, bias5, cA, hA);

  // 3) B=4096: RT=2 row-affine compose: (hA,cA)@8192 -> (cB,hB)@4096
  k_compose_rt2<<<512, 256, 0, stream>>>(hA, cA, Wcf, bias5, cB, hB, 4096);

  // 4) Levels 2048,1024: (hB,cB)@4096 -> (cA,hA)@1024
  k_fusen<2><<<64, 256, 0, stream>>>(hB, cB, Wcf, bias5, cA, hA, nullptr, 4096);

  // 5) Levels 512,256: (hA,cA)@1024 -> (cB,hB)@256
  k_fusen<2><<<16, 256, 0, stream>>>(hA, cA, Wcf, bias5, cB, hB, nullptr, 1024);

  // 6) Levels 128,64: (hB,cB)@256 -> (cA,hA)@64
  k_fusen<2><<<4, 256, 0, stream>>>(hB, cB, Wcf, bias5, cA, hA, nullptr, 256);

  // 7) Levels 32..1: (hA,cA)@64 -> out (c at [0:256], h at [256:512])
  k_fusen<6><<<1, 256, 0, stream>>>(hA, cA, Wcf, bias5, nullptr, nullptr, out, 64);
}

// Round 9
// 275.145 us; speedup vs baseline: 8.5619x; 8.5619x over previous
//
#include <hip/hip_runtime.h>
#include <math.h>

// BinaryTreeLSTM on MI355X — R12.
// vs R11 (2355us — single-block fusion REJECTED: full-Wcf per block thru one
// CU's ~150GB/s L2 path; grp-sliced many-CU streaming is mandatory => level
// boundary = kernel boundary). Base = R9 (227us). Changes:
//  (1) prep1 ELIMINATED: leaf blocks stage A (64 embs rows, f32->bf16) and
//      B (grp's 48 Wx rows) into LDS (71KB, A padded to 328/row = optimal
//      8-clk b128), MFMA from LDS. rb=b&127 => embs XCD-local (1.2MB/XCD).
//      Wcf/bias5 roles ride in the same dispatch (independent of leaf out).
//  (2) ksplit replaces rt2 at B=4096 (4-kc chains + 4x waves won at <=2048;
//      same mechanism). Producer/consumer tile map keeps h XCD-local.
// Dispatches: front(leaf+Wcf+bias5), ksplit x13 = 14.

#define MEM 256

typedef __attribute__((ext_vector_type(8))) short bf16x8;
typedef __attribute__((ext_vector_type(4))) float f32x4;

__device__ __forceinline__ float sigf(float x) { return 1.0f / (1.0f + __expf(-x)); }

__device__ __forceinline__ unsigned short f2b(float f) {
  unsigned int u = __float_as_uint(f);
  u = (u + 0x7FFFu + ((u >> 16) & 1u)) >> 16;
  return (unsigned short)u;
}

// 8 consecutive f32 -> bf16x8
__device__ __forceinline__ bf16x8 c8(const float* __restrict__ p) {
  float4 f0 = *(const float4*)(p);
  float4 f1 = *(const float4*)(p + 4);
  bf16x8 r;
  r[0] = (short)f2b(f0.x); r[1] = (short)f2b(f0.y);
  r[2] = (short)f2b(f0.z); r[3] = (short)f2b(f0.w);
  r[4] = (short)f2b(f1.x); r[5] = (short)f2b(f1.y);
  r[6] = (short)f2b(f1.z); r[7] = (short)f2b(f1.w);
  return r;
}

// 8 consecutive k from a 300-long f32 row, zero-padded past 300
__device__ __forceinline__ bf16x8 g8(const float* __restrict__ rp, int k0) {
  if (k0 + 8 <= 300) return c8(rp + k0);
  bf16x8 r;
#pragma unroll
  for (int j = 0; j < 8; j++) {
    int k = k0 + j;
    r[j] = (k < 300) ? (short)f2b(rp[k]) : (short)0;
  }
  return r;
}

// ---- Front: leaf (0..2047, LDS-staged) | Wcf shuffle (2048..2367) | bias5 ----
#define NB_LEAF 2048
#define NB_WCF 320   // 1280*512/2048
// LDS: A [64][328] ushort = 41984B; B [30][512] ushort = 30720B; total 72704B
__global__ __launch_bounds__(256) void k_front(
    const float* __restrict__ embs, const float* __restrict__ Wx,
    const float* __restrict__ bx, const float* __restrict__ Wl,
    const float* __restrict__ Wr, const float* __restrict__ emb_last,
    unsigned short* __restrict__ Wcf, float* __restrict__ bias5,
    float* __restrict__ cO, unsigned short* __restrict__ hO) {
  __shared__ __align__(16) unsigned char smem[72704];
  int b = blockIdx.x, tid = threadIdx.x;
  if (b < NB_LEAF) {
    int rb = b & 127;      // row-block 0..127 (64 rows each) -> XCD = b%8 = rb%8
    int grp = b >> 7;      // 0..15
    unsigned short* As = (unsigned short*)smem;            // [64][328]
    unsigned short* Bs = (unsigned short*)(smem + 41984);  // [kc*3+gate][512]
    const int gmap[3] = {0, 1, 3};
    // Stage A: 64 rows x 320 (zero-pad 300..319); pad row to 328
    for (int i = tid; i < 2560; i += 256) {
      int idx8 = i * 8;
      int r = idx8 / 320, k0 = idx8 - r * 320;
      *(bf16x8*)(As + r * 328 + k0) = g8(embs + (size_t)(rb * 64 + r) * 300, k0);
    }
    // Stage B: 30 frags x 512; frag f=kc*3+gate, elem[l*8+j]=W[k][n]
    for (int i = tid; i < 1920; i += 256) {
      int idx8 = i * 8;
      int f = idx8 >> 9, rr = idx8 & 511;
      int kc = f / 3, gate = f - kc * 3;
      int ll = rr >> 3;
      int k0 = kc * 32 + ((ll >> 4) << 3);
      int n = gmap[gate] * 256 + grp * 16 + (ll & 15);
      *(bf16x8*)(Bs + idx8) = g8(Wx + n * 300, k0);
    }
    __syncthreads();

    int lane = tid & 63, wave = tid >> 6;
    int m = lane & 15, quad = lane >> 4;
    f32x4 acc0 = {0.f, 0.f, 0.f, 0.f}, acc1 = acc0, acc2 = acc0;
    const unsigned short* arow = As + (wave * 16 + m) * 328 + quad * 8;
#pragma unroll
    for (int kc = 0; kc < 10; kc++) {
      bf16x8 a = *(const bf16x8*)(arow + kc * 32);
      const unsigned short* bp = Bs + (kc * 3) * 512 + lane * 8;
      bf16x8 b0 = *(const bf16x8*)(bp);
      bf16x8 b1 = *(const bf16x8*)(bp + 512);
      bf16x8 b2 = *(const bf16x8*)(bp + 1024);
      acc0 = __builtin_amdgcn_mfma_f32_16x16x32_bf16(a, b0, acc0, 0, 0, 0);
      acc1 = __builtin_amdgcn_mfma_f32_16x16x32_bf16(a, b1, acc1, 0, 0, 0);
      acc2 = __builtin_amdgcn_mfma_f32_16x16x32_bf16(a, b2, acc2, 0, 0, 0);
    }
    int col = grp * 16 + m;
    float b0 = bx[col], b1 = bx[256 + col], b3 = bx[768 + col];
#pragma unroll
    for (int reg = 0; reg < 4; reg++) {
      int row = rb * 64 + wave * 16 + quad * 4 + reg;
      float u = tanhf(acc0[reg] + b0);
      float ig = sigf(acc1[reg] + b1);
      float o = sigf(acc2[reg] + b3);
      float c = ig * u;
      cO[row * MEM + col] = c;
      hO[row * MEM + col] = f2b(o * tanhf(c));
    }
  } else if (b < NB_LEAF + NB_WCF) {
    int idx8 = ((b - NB_LEAF) * 256 + tid) * 8;  // 1280*512
    int f = idx8 >> 9, rr = idx8 & 511;
    int lane = rr >> 3;
    int gate = f % 5, t = f / 5;
    int grp = t & 15, kc = t >> 4;
    int k0 = kc * 32 + ((lane >> 4) << 3);
    int n = gate * 256 + (grp << 4) + (lane & 15);
    const float* src = (k0 < 256) ? (Wl + n * 256 + k0) : (Wr + n * 256 + (k0 - 256));
    *(bf16x8*)(Wcf + idx8) = c8(src);
  } else {
    int g = b - (NB_LEAF + NB_WCF);  // 0..4
    float* er = (float*)smem;        // 300 floats
    for (int k = tid; k < 300; k += 256) er[k] = emb_last[k];
    __syncthreads();
    const int map[5] = {0, 1, 2, 2, 3};
    int wrow = map[g] * 256 + tid;
    const float* w = Wx + wrow * 300;
    float s = bx[wrow];
    for (int k = 0; k < 300; k++) s += er[k] * w[k];
    bias5[g * 256 + tid] = s;
  }
}

// ---- K-split compose (all levels): grid(ceil(tiles/2),16) ----
// Block = (tile-pair tp, grp); wave w covers kc in [4w,4w+4); LDS reduce.
__global__ __launch_bounds__(256, 4) void k_compose_ksplit(
    const unsigned short* __restrict__ hprev, const float* __restrict__ cprev,
    const unsigned short* __restrict__ Wcf, const float* __restrict__ bias5,
    float* __restrict__ cO, unsigned short* __restrict__ hO,
    float* __restrict__ hOf, int B) {
  __shared__ __align__(16) float lds[4 * 2 * 5 * 64 * 4];  // 40KB
  int tid = threadIdx.x;
  int lane = tid & 63, wave = tid >> 6;
  int grp = blockIdx.y;
  int tp = blockIdx.x;
  int m = lane & 15, quad = lane >> 4;
  int tiles = (B + 15) >> 4;
  const bf16x8 zz = {0, 0, 0, 0, 0, 0, 0, 0};

  f32x4 acc[2][5];
  bool act[2], ok[2];
  bf16x8 av[2][4];  // A prefetched: [tile][kcl]
#pragma unroll
  for (int t = 0; t < 2; t++) {
    int gt = 2 * tp + t;
    act[t] = (gt < tiles);
    int ra = gt * 16 + m;
    ok[t] = act[t] && (ra < B);
    const unsigned short* ar = hprev + (size_t)ra * 512 + quad * 8;
#pragma unroll
    for (int kcl = 0; kcl < 4; kcl++)
      av[t][kcl] = ok[t] ? *(const bf16x8*)(ar + (wave * 4 + kcl) * 32) : zz;
#pragma unroll
    for (int q = 0; q < 5; q++) acc[t][q] = (f32x4){0.f, 0.f, 0.f, 0.f};
  }

#pragma unroll
  for (int kcl = 0; kcl < 4; kcl++) {
    int kc = wave * 4 + kcl;
    const unsigned short* bp = Wcf + ((kc * 16 + grp) * 5) * 512 + lane * 8;
    bf16x8 b0 = *(const bf16x8*)(bp);
    bf16x8 b1 = *(const bf16x8*)(bp + 512);
    bf16x8 b2 = *(const bf16x8*)(bp + 1024);
    bf16x8 b3 = *(const bf16x8*)(bp + 1536);
    bf16x8 b4 = *(const bf16x8*)(bp + 2048);
#pragma unroll
    for (int t = 0; t < 2; t++) {
      if (act[t]) {
        acc[t][0] = __builtin_amdgcn_mfma_f32_16x16x32_bf16(av[t][kcl], b0, acc[t][0], 0, 0, 0);
        acc[t][1] = __builtin_amdgcn_mfma_f32_16x16x32_bf16(av[t][kcl], b1, acc[t][1], 0, 0, 0);
        acc[t][2] = __builtin_amdgcn_mfma_f32_16x16x32_bf16(av[t][kcl], b2, acc[t][2], 0, 0, 0);
        acc[t][3] = __builtin_amdgcn_mfma_f32_16x16x32_bf16(av[t][kcl], b3, acc[t][3], 0, 0, 0);
        acc[t][4] = __builtin_amdgcn_mfma_f32_16x16x32_bf16(av[t][kcl], b4, acc[t][4], 0, 0, 0);
      }
    }
  }
#pragma unroll
  for (int t = 0; t < 2; t++)
    if (act[t])
#pragma unroll
      for (int q = 0; q < 5; q++)
        *(f32x4*)&lds[(((wave * 2 + t) * 5 + q) * 64 + lane) * 4] = acc[t][q];
  __syncthreads();

  if (wave < 2 && act[wave]) {
    int t = wave;
    int gt = 2 * tp + t;
    int col = grp * 16 + m;
    float b0 = bias5[col], b1 = bias5[256 + col], b2 = bias5[512 + col];
    float b3 = bias5[768 + col], b4 = bias5[1024 + col];
    f32x4 s[5];
#pragma unroll
    for (int q = 0; q < 5; q++) {
      s[q] = *(const f32x4*)&lds[(((0 * 2 + t) * 5 + q) * 64 + lane) * 4];
#pragma unroll
      for (int v = 1; v < 4; v++) {
        f32x4 p = *(const f32x4*)&lds[(((v * 2 + t) * 5 + q) * 64 + lane) * 4];
        s[q][0] += p[0]; s[q][1] += p[1]; s[q][2] += p[2]; s[q][3] += p[3];
      }
    }
#pragma unroll
    for (int reg = 0; reg < 4; reg++) {
      int row = gt * 16 + quad * 4 + reg;
      if (row >= B) continue;
      float u = tanhf(s[0][reg] + b0);
      float ig = sigf(s[1][reg] + b1);
      float lf = sigf(s[2][reg] + b2);
      float rf = sigf(s[3][reg] + b3);
      float o = sigf(s[4][reg] + b4);
      float lc = cprev[(2 * row) * MEM + col];
      float rc = cprev[(2 * row + 1) * MEM + col];
      float c = ig * u + lf * lc + rf * rc;
      float h = o * tanhf(c);
      cO[row * MEM + col] = c;
      hO[row * MEM + col] = f2b(h);
      if (hOf) hOf[row * MEM + col] = h;
    }
  }
}

extern "C" void kernel_launch(void* const* d_in, const int* in_sizes, int n_in,
                              void* d_out, int out_size, void* d_ws, size_t ws_size,
                              hipStream_t stream) {
  const float* embs = (const float*)d_in[0];
  const float* Wx = (const float*)d_in[1];
  const float* bx = (const float*)d_in[2];
  const float* Wl = (const float*)d_in[3];
  const float* Wr = (const float*)d_in[4];
  const float* emb_table = (const float*)d_in[5];
  float* out = (float*)d_out;

  // Workspace layout (~19.5 MB)
  float* ws = (float*)d_ws;
  float* cA = ws;                               // 8192*256 f32
  float* cB = cA + 8192 * 256;                  // 4096*256 f32
  float* bias5 = cB + 4096 * 256;               // 1280 f32
  unsigned short* hA = (unsigned short*)(bias5 + 1280);  // 8192*256 bf16
  unsigned short* hB = hA + 8192 * 256;                  // 4096*256 bf16
  unsigned short* Wcf = hB + 4096 * 256;                 // 1280*512

  // 1) Front: leaf (staged from f32) + Wcf shuffle + bias5 -> cA, hA
  k_front<<<NB_LEAF + NB_WCF + 5, 256, 0, stream>>>(
      embs, Wx, bx, Wl, Wr, emb_table + (in_sizes[5] - 300),
      Wcf, bias5, cA, hA);

  // 2) 13 tree levels, ksplit each
  const float* cs = cA;
  const unsigned short* hs = hA;
  int B = 4096;
  int lvl = 0;
  while (B >= 1) {
    float* dc;
    unsigned short* dh;
    float* dhf = nullptr;
    if (B == 1) {
      dc = out;
      dh = hB;  // dummy bf16 sink
      dhf = out + 256;
    } else if ((lvl & 1) == 0) {
      dc = cB; dh = hB;
    } else {
      dc = cA; dh = hA;
    }
    int tiles = (B + 15) / 16;
    int gx = (tiles + 1) / 2;
    k_compose_ksplit<<<dim3(gx, 16), 256, 0, stream>>>(
        hs, cs, Wcf, bias5, dc, dh, dhf, B);
    cs = dc;
    hs = dh;
    B >>= 1;
    lvl++;
  }
}

// Round 10
// 232.049 us; speedup vs baseline: 10.1520x; 1.1857x over previous
//
#include <hip/hip_runtime.h>
#include <math.h>

// BinaryTreeLSTM on MI355X — R13.
// vs R12 (275us — staged leaf REJECTED per pre-registration: 16x redundant
// f32->bf16 + LDS conflicts = 87us k_front): revert to R9's proven front-end
// (prep1 + leaf_fused, 227.6us base). Single change vs R9: ksplit replaces
// rt2 at B=4096 (R12 arithmetic: ks@4096 - rt2 = -10..-15us hidden inside
// the k_front regression; mechanism proven at 2048: 4-kc chains + 4x waves).
// Dispatches: prep1, leaf_fused, ksplit x13 = 15.

#define MEM 256

typedef __attribute__((ext_vector_type(8))) short bf16x8;
typedef __attribute__((ext_vector_type(4))) float f32x4;

__device__ __forceinline__ float sigf(float x) { return 1.0f / (1.0f + __expf(-x)); }

__device__ __forceinline__ unsigned short f2b(float f) {
  unsigned int u = __float_as_uint(f);
  u = (u + 0x7FFFu + ((u >> 16) & 1u)) >> 16;
  return (unsigned short)u;
}

// 8 consecutive f32 -> bf16x8
__device__ __forceinline__ bf16x8 c8(const float* __restrict__ p) {
  float4 f0 = *(const float4*)(p);
  float4 f1 = *(const float4*)(p + 4);
  bf16x8 r;
  r[0] = (short)f2b(f0.x); r[1] = (short)f2b(f0.y);
  r[2] = (short)f2b(f0.z); r[3] = (short)f2b(f0.w);
  r[4] = (short)f2b(f1.x); r[5] = (short)f2b(f1.y);
  r[6] = (short)f2b(f1.z); r[7] = (short)f2b(f1.w);
  return r;
}

// 8 consecutive k from a 300-long f32 row, zero-padded past 300
__device__ __forceinline__ bf16x8 g8(const float* __restrict__ rp, int k0) {
  if (k0 + 8 <= 300) return c8(rp + k0);
  bf16x8 r;
#pragma unroll
  for (int j = 0; j < 8; j++) {
    int k = k0 + j;
    r[j] = (k < 300) ? (short)f2b(rp[k]) : (short)0;
  }
  return r;
}

// ---- Prep1: eb (embs->bf16) | Wxf shuffle ----
#define NB_EB 1280   // 8192*320/2048
#define NB_WXF 120   // 480*512/2048
__global__ __launch_bounds__(256) void k_prep1(
    const float* __restrict__ embs, const float* __restrict__ Wx,
    unsigned short* __restrict__ eb, unsigned short* __restrict__ Wxf) {
  int b = blockIdx.x, tid = threadIdx.x;
  if (b < NB_EB) {
    int idx8 = (b * 256 + tid) * 8;       // 8192*320
    int row = idx8 / 320;
    int k0 = idx8 - row * 320;
    *(bf16x8*)(eb + idx8) = g8(embs + row * 300, k0);
  } else {
    int idx8 = ((b - NB_EB) * 256 + tid) * 8;  // 480*512
    int f = idx8 >> 9, rr = idx8 & 511;
    int lane = rr >> 3;
    int gate = f % 3, t = f / 3;
    int grp = t & 15, kc = t >> 4;
    int k0 = kc * 32 + ((lane >> 4) << 3);
    const int gmap[3] = {0, 1, 3};
    int n = gmap[gate] * 256 + (grp << 4) + (lane & 15);
    *(bf16x8*)(Wxf + idx8) = g8(Wx + n * 300, k0);
  }
}

// ---- Leaf (0..1023) | Wcf shuffle (1024..1343) | bias5 (1344..1348) ----
#define NB_LEAF 1024
#define NB_WCF 320   // 1280*512/2048
__global__ __launch_bounds__(256) void k_leaf_fused(
    const unsigned short* __restrict__ eb, const unsigned short* __restrict__ Wxf,
    const float* __restrict__ bx, const float* __restrict__ Wx,
    const float* __restrict__ Wl, const float* __restrict__ Wr,
    const float* __restrict__ emb_last,
    unsigned short* __restrict__ Wcf, float* __restrict__ bias5,
    float* __restrict__ cO, unsigned short* __restrict__ hO) {
  int b = blockIdx.x, tid = threadIdx.x;
  if (b < NB_LEAF) {
    int slice = b & 7, rest = b >> 3;
    int rowblock = slice * 8 + (rest & 7);
    int grp = rest >> 3;
    int lane = tid & 63, wave = tid >> 6;
    int tb = (rowblock * 4 + wave) * 2;
    int m = lane & 15, quad = lane >> 4;

    f32x4 acc[2][3];
#pragma unroll
    for (int rt = 0; rt < 2; rt++)
#pragma unroll
      for (int g = 0; g < 3; g++) acc[rt][g] = (f32x4){0.f, 0.f, 0.f, 0.f};

    const unsigned short* ar0 = eb + (tb * 16 + m) * 320 + quad * 8;
    const unsigned short* ar1 = eb + ((tb + 1) * 16 + m) * 320 + quad * 8;
#pragma unroll
    for (int kc = 0; kc < 10; kc++) {
      const unsigned short* bp = Wxf + ((kc * 16 + grp) * 3) * 512 + lane * 8;
      bf16x8 b0 = *(const bf16x8*)(bp);
      bf16x8 b1 = *(const bf16x8*)(bp + 512);
      bf16x8 b2 = *(const bf16x8*)(bp + 1024);
      bf16x8 a0 = *(const bf16x8*)(ar0 + kc * 32);
      bf16x8 a1 = *(const bf16x8*)(ar1 + kc * 32);
      acc[0][0] = __builtin_amdgcn_mfma_f32_16x16x32_bf16(a0, b0, acc[0][0], 0, 0, 0);
      acc[0][1] = __builtin_amdgcn_mfma_f32_16x16x32_bf16(a0, b1, acc[0][1], 0, 0, 0);
      acc[0][2] = __builtin_amdgcn_mfma_f32_16x16x32_bf16(a0, b2, acc[0][2], 0, 0, 0);
      acc[1][0] = __builtin_amdgcn_mfma_f32_16x16x32_bf16(a1, b0, acc[1][0], 0, 0, 0);
      acc[1][1] = __builtin_amdgcn_mfma_f32_16x16x32_bf16(a1, b1, acc[1][1], 0, 0, 0);
      acc[1][2] = __builtin_amdgcn_mfma_f32_16x16x32_bf16(a1, b2, acc[1][2], 0, 0, 0);
    }
    int col = grp * 16 + m;
    float b0 = bx[col], b1 = bx[256 + col], b3 = bx[768 + col];
#pragma unroll
    for (int rt = 0; rt < 2; rt++) {
#pragma unroll
      for (int reg = 0; reg < 4; reg++) {
        int row = (tb + rt) * 16 + quad * 4 + reg;
        float u = tanhf(acc[rt][0][reg] + b0);
        float ig = sigf(acc[rt][1][reg] + b1);
        float o = sigf(acc[rt][2][reg] + b3);
        float c = ig * u;
        cO[row * MEM + col] = c;
        hO[row * MEM + col] = f2b(o * tanhf(c));
      }
    }
  } else if (b < NB_LEAF + NB_WCF) {
    int idx8 = ((b - NB_LEAF) * 256 + tid) * 8;  // 1280*512
    int f = idx8 >> 9, rr = idx8 & 511;
    int lane = rr >> 3;
    int gate = f % 5, t = f / 5;
    int grp = t & 15, kc = t >> 4;
    int k0 = kc * 32 + ((lane >> 4) << 3);
    int n = gate * 256 + (grp << 4) + (lane & 15);
    const float* src = (k0 < 256) ? (Wl + n * 256 + k0) : (Wr + n * 256 + (k0 - 256));
    *(bf16x8*)(Wcf + idx8) = c8(src);
  } else {
    int g = b - (NB_LEAF + NB_WCF);  // 0..4
    __shared__ float er[300];
    for (int k = tid; k < 300; k += 256) er[k] = emb_last[k];
    __syncthreads();
    const int map[5] = {0, 1, 2, 2, 3};
    int wrow = map[g] * 256 + tid;
    const float* w = Wx + wrow * 300;
    float s = bx[wrow];
    for (int k = 0; k < 300; k++) s += er[k] * w[k];
    bias5[g * 256 + tid] = s;
  }
}

// ---- K-split compose (all levels): grid(ceil(tiles/2),16) ----
// Block = (tile-pair tp, grp); wave w covers kc in [4w,4w+4); LDS reduce.
__global__ __launch_bounds__(256, 4) void k_compose_ksplit(
    const unsigned short* __restrict__ hprev, const float* __restrict__ cprev,
    const unsigned short* __restrict__ Wcf, const float* __restrict__ bias5,
    float* __restrict__ cO, unsigned short* __restrict__ hO,
    float* __restrict__ hOf, int B) {
  __shared__ __align__(16) float lds[4 * 2 * 5 * 64 * 4];  // 40KB
  int tid = threadIdx.x;
  int lane = tid & 63, wave = tid >> 6;
  int grp = blockIdx.y;
  int tp = blockIdx.x;
  int m = lane & 15, quad = lane >> 4;
  int tiles = (B + 15) >> 4;
  const bf16x8 zz = {0, 0, 0, 0, 0, 0, 0, 0};

  f32x4 acc[2][5];
  bool act[2], ok[2];
  bf16x8 av[2][4];  // A prefetched: [tile][kcl]
#pragma unroll
  for (int t = 0; t < 2; t++) {
    int gt = 2 * tp + t;
    act[t] = (gt < tiles);
    int ra = gt * 16 + m;
    ok[t] = act[t] && (ra < B);
    const unsigned short* ar = hprev + (size_t)ra * 512 + quad * 8;
#pragma unroll
    for (int kcl = 0; kcl < 4; kcl++)
      av[t][kcl] = ok[t] ? *(const bf16x8*)(ar + (wave * 4 + kcl) * 32) : zz;
#pragma unroll
    for (int q = 0; q < 5; q++) acc[t][q] = (f32x4){0.f, 0.f, 0.f, 0.f};
  }

#pragma unroll
  for (int kcl = 0; kcl < 4; kcl++) {
    int kc = wave * 4 + kcl;
    const unsigned short* bp = Wcf + ((kc * 16 + grp) * 5) * 512 + lane * 8;
    bf16x8 b0 = *(const bf16x8*)(bp);
    bf16x8 b1 = *(const bf16x8*)(bp + 512);
    bf16x8 b2 = *(const bf16x8*)(bp + 1024);
    bf16x8 b3 = *(const bf16x8*)(bp + 1536);
    bf16x8 b4 = *(const bf16x8*)(bp + 2048);
#pragma unroll
    for (int t = 0; t < 2; t++) {
      if (act[t]) {
        acc[t][0] = __builtin_amdgcn_mfma_f32_16x16x32_bf16(av[t][kcl], b0, acc[t][0], 0, 0, 0);
        acc[t][1] = __builtin_amdgcn_mfma_f32_16x16x32_bf16(av[t][kcl], b1, acc[t][1], 0, 0, 0);
        acc[t][2] = __builtin_amdgcn_mfma_f32_16x16x32_bf16(av[t][kcl], b2, acc[t][2], 0, 0, 0);
        acc[t][3] = __builtin_amdgcn_mfma_f32_16x16x32_bf16(av[t][kcl], b3, acc[t][3], 0, 0, 0);
        acc[t][4] = __builtin_amdgcn_mfma_f32_16x16x32_bf16(av[t][kcl], b4, acc[t][4], 0, 0, 0);
      }
    }
  }
#pragma unroll
  for (int t = 0; t < 2; t++)
    if (act[t])
#pragma unroll
      for (int q = 0; q < 5; q++)
        *(f32x4*)&lds[(((wave * 2 + t) * 5 + q) * 64 + lane) * 4] = acc[t][q];
  __syncthreads();

  if (wave < 2 && act[wave]) {
    int t = wave;
    int gt = 2 * tp + t;
    int col = grp * 16 + m;
    float b0 = bias5[col], b1 = bias5[256 + col], b2 = bias5[512 + col];
    float b3 = bias5[768 + col], b4 = bias5[1024 + col];
    f32x4 s[5];
#pragma unroll
    for (int q = 0; q < 5; q++) {
      s[q] = *(const f32x4*)&lds[(((0 * 2 + t) * 5 + q) * 64 + lane) * 4];
#pragma unroll
      for (int v = 1; v < 4; v++) {
        f32x4 p = *(const f32x4*)&lds[(((v * 2 + t) * 5 + q) * 64 + lane) * 4];
        s[q][0] += p[0]; s[q][1] += p[1]; s[q][2] += p[2]; s[q][3] += p[3];
      }
    }
#pragma unroll
    for (int reg = 0; reg < 4; reg++) {
      int row = gt * 16 + quad * 4 + reg;
      if (row >= B) continue;
      float u = tanhf(s[0][reg] + b0);
      float ig = sigf(s[1][reg] + b1);
      float lf = sigf(s[2][reg] + b2);
      float rf = sigf(s[3][reg] + b3);
      float o = sigf(s[4][reg] + b4);
      float lc = cprev[(2 * row) * MEM + col];
      float rc = cprev[(2 * row + 1) * MEM + col];
      float c = ig * u + lf * lc + rf * rc;
      float h = o * tanhf(c);
      cO[row * MEM + col] = c;
      hO[row * MEM + col] = f2b(h);
      if (hOf) hOf[row * MEM + col] = h;
    }
  }
}

extern "C" void kernel_launch(void* const* d_in, const int* in_sizes, int n_in,
                              void* d_out, int out_size, void* d_ws, size_t ws_size,
                              hipStream_t stream) {
  const float* embs = (const float*)d_in[0];
  const float* Wx = (const float*)d_in[1];
  const float* bx = (const float*)d_in[2];
  const float* Wl = (const float*)d_in[3];
  const float* Wr = (const float*)d_in[4];
  const float* emb_table = (const float*)d_in[5];
  float* out = (float*)d_out;

  // Workspace layout (~25 MB)
  float* ws = (float*)d_ws;
  float* cA = ws;                               // 8192*256 f32
  float* cB = cA + 8192 * 256;                  // 4096*256 f32
  float* bias5 = cB + 4096 * 256;               // 1280 f32
  unsigned short* hA = (unsigned short*)(bias5 + 1280);  // 8192*256 bf16
  unsigned short* hB = hA + 8192 * 256;                  // 4096*256 bf16
  unsigned short* Wcf = hB + 4096 * 256;                 // 1280*512
  unsigned short* Wxf = Wcf + 1280 * 512;                // 480*512
  unsigned short* eb = Wxf + 480 * 512;                  // 8192*320

  // 1) Prep1: eb + Wxf (1400 blocks)
  k_prep1<<<NB_EB + NB_WXF, 256, 0, stream>>>(embs, Wx, eb, Wxf);

  // 2) Leaf (+ Wcf shuffle + bias5 overlapped) -> cA, hA (8192 rows)
  k_leaf_fused<<<NB_LEAF + NB_WCF + 5, 256, 0, stream>>>(
      eb, Wxf, bx, Wx, Wl, Wr, emb_table + (in_sizes[5] - 300),
      Wcf, bias5, cA, hA);

  // 3) 13 tree levels, ksplit each (B=4096 included — replaces rt2)
  const float* cs = cA;
  const unsigned short* hs = hA;
  int B = 4096;
  int lvl = 0;
  while (B >= 1) {
    float* dc;
    unsigned short* dh;
    float* dhf = nullptr;
    if (B == 1) {
      dc = out;
      dh = hB;  // dummy bf16 sink
      dhf = out + 256;
    } else if ((lvl & 1) == 0) {
      dc = cB; dh = hB;
    } else {
      dc = cA; dh = hA;
    }
    int tiles = (B + 15) / 16;
    int gx = (tiles + 1) / 2;
    k_compose_ksplit<<<dim3(gx, 16), 256, 0, stream>>>(
        hs, cs, Wcf, bias5, dc, dh, dhf, B);
    cs = dc;
    hs = dh;
    B >>= 1;
    lvl++;
  }
}

// Round 11
// 232.022 us; speedup vs baseline: 10.1532x; 1.0001x over previous
//
#include <hip/hip_runtime.h>
#include <math.h>

// BinaryTreeLSTM on MI355X — R14 = exact revert to R9 (best verified: 227.6us).
// R13 (ksplit@4096) = 232.0 — pre-registered read: rt2 wins at 4096 (waves
// already plentiful there; ksplit only pays where wave count is starved).
// Structural constraints established this session:
//  - device-wide sync ~9-10us/level (cg AND flag-barrier agree) >= launch gap
//    ~4-6us => in-kernel level fusion loses (R4, R10).
//  - level weights (1.3MB) must stream via many CUs => grp-sliced grid =>
//    level boundary = kernel boundary (R11: 1-block fusion 916us).
//  - per-grp re-staging/conversion of shared data = 16x redundancy (R7, R12).
// Dispatches: prep1, leaf_fused(+Wcf+bias5), rt2(4096), ksplit x12 = 15.

#define MEM 256

typedef __attribute__((ext_vector_type(8))) short bf16x8;
typedef __attribute__((ext_vector_type(4))) float f32x4;

__device__ __forceinline__ float sigf(float x) { return 1.0f / (1.0f + __expf(-x)); }

__device__ __forceinline__ unsigned short f2b(float f) {
  unsigned int u = __float_as_uint(f);
  u = (u + 0x7FFFu + ((u >> 16) & 1u)) >> 16;
  return (unsigned short)u;
}

// 8 consecutive f32 -> bf16x8
__device__ __forceinline__ bf16x8 c8(const float* __restrict__ p) {
  float4 f0 = *(const float4*)(p);
  float4 f1 = *(const float4*)(p + 4);
  bf16x8 r;
  r[0] = (short)f2b(f0.x); r[1] = (short)f2b(f0.y);
  r[2] = (short)f2b(f0.z); r[3] = (short)f2b(f0.w);
  r[4] = (short)f2b(f1.x); r[5] = (short)f2b(f1.y);
  r[6] = (short)f2b(f1.z); r[7] = (short)f2b(f1.w);
  return r;
}

// 8 consecutive k from a 300-long f32 row, zero-padded past 300
__device__ __forceinline__ bf16x8 g8(const float* __restrict__ rp, int k0) {
  if (k0 + 8 <= 300) return c8(rp + k0);
  bf16x8 r;
#pragma unroll
  for (int j = 0; j < 8; j++) {
    int k = k0 + j;
    r[j] = (k < 300) ? (short)f2b(rp[k]) : (short)0;
  }
  return r;
}

// ---- Prep1: eb (embs->bf16) | Wxf shuffle ----
#define NB_EB 1280   // 8192*320/2048
#define NB_WXF 120   // 480*512/2048
__global__ __launch_bounds__(256) void k_prep1(
    const float* __restrict__ embs, const float* __restrict__ Wx,
    unsigned short* __restrict__ eb, unsigned short* __restrict__ Wxf) {
  int b = blockIdx.x, tid = threadIdx.x;
  if (b < NB_EB) {
    int idx8 = (b * 256 + tid) * 8;       // 8192*320
    int row = idx8 / 320;
    int k0 = idx8 - row * 320;
    *(bf16x8*)(eb + idx8) = g8(embs + row * 300, k0);
  } else {
    int idx8 = ((b - NB_EB) * 256 + tid) * 8;  // 480*512
    int f = idx8 >> 9, rr = idx8 & 511;
    int lane = rr >> 3;
    int gate = f % 3, t = f / 3;
    int grp = t & 15, kc = t >> 4;
    int k0 = kc * 32 + ((lane >> 4) << 3);
    const int gmap[3] = {0, 1, 3};
    int n = gmap[gate] * 256 + (grp << 4) + (lane & 15);
    *(bf16x8*)(Wxf + idx8) = g8(Wx + n * 300, k0);
  }
}

// ---- Leaf (0..1023) | Wcf shuffle (1024..1343) | bias5 (1344..1348) ----
#define NB_LEAF 1024
#define NB_WCF 320   // 1280*512/2048
__global__ __launch_bounds__(256) void k_leaf_fused(
    const unsigned short* __restrict__ eb, const unsigned short* __restrict__ Wxf,
    const float* __restrict__ bx, const float* __restrict__ Wx,
    const float* __restrict__ Wl, const float* __restrict__ Wr,
    const float* __restrict__ emb_last,
    unsigned short* __restrict__ Wcf, float* __restrict__ bias5,
    float* __restrict__ cO, unsigned short* __restrict__ hO) {
  int b = blockIdx.x, tid = threadIdx.x;
  if (b < NB_LEAF) {
    int slice = b & 7, rest = b >> 3;
    int rowblock = slice * 8 + (rest & 7);
    int grp = rest >> 3;
    int lane = tid & 63, wave = tid >> 6;
    int tb = (rowblock * 4 + wave) * 2;
    int m = lane & 15, quad = lane >> 4;

    f32x4 acc[2][3];
#pragma unroll
    for (int rt = 0; rt < 2; rt++)
#pragma unroll
      for (int g = 0; g < 3; g++) acc[rt][g] = (f32x4){0.f, 0.f, 0.f, 0.f};

    const unsigned short* ar0 = eb + (tb * 16 + m) * 320 + quad * 8;
    const unsigned short* ar1 = eb + ((tb + 1) * 16 + m) * 320 + quad * 8;
#pragma unroll
    for (int kc = 0; kc < 10; kc++) {
      const unsigned short* bp = Wxf + ((kc * 16 + grp) * 3) * 512 + lane * 8;
      bf16x8 b0 = *(const bf16x8*)(bp);
      bf16x8 b1 = *(const bf16x8*)(bp + 512);
      bf16x8 b2 = *(const bf16x8*)(bp + 1024);
      bf16x8 a0 = *(const bf16x8*)(ar0 + kc * 32);
      bf16x8 a1 = *(const bf16x8*)(ar1 + kc * 32);
      acc[0][0] = __builtin_amdgcn_mfma_f32_16x16x32_bf16(a0, b0, acc[0][0], 0, 0, 0);
      acc[0][1] = __builtin_amdgcn_mfma_f32_16x16x32_bf16(a0, b1, acc[0][1], 0, 0, 0);
      acc[0][2] = __builtin_amdgcn_mfma_f32_16x16x32_bf16(a0, b2, acc[0][2], 0, 0, 0);
      acc[1][0] = __builtin_amdgcn_mfma_f32_16x16x32_bf16(a1, b0, acc[1][0], 0, 0, 0);
      acc[1][1] = __builtin_amdgcn_mfma_f32_16x16x32_bf16(a1, b1, acc[1][1], 0, 0, 0);
      acc[1][2] = __builtin_amdgcn_mfma_f32_16x16x32_bf16(a1, b2, acc[1][2], 0, 0, 0);
    }
    int col = grp * 16 + m;
    float b0 = bx[col], b1 = bx[256 + col], b3 = bx[768 + col];
#pragma unroll
    for (int rt = 0; rt < 2; rt++) {
#pragma unroll
      for (int reg = 0; reg < 4; reg++) {
        int row = (tb + rt) * 16 + quad * 4 + reg;
        float u = tanhf(acc[rt][0][reg] + b0);
        float ig = sigf(acc[rt][1][reg] + b1);
        float o = sigf(acc[rt][2][reg] + b3);
        float c = ig * u;
        cO[row * MEM + col] = c;
        hO[row * MEM + col] = f2b(o * tanhf(c));
      }
    }
  } else if (b < NB_LEAF + NB_WCF) {
    int idx8 = ((b - NB_LEAF) * 256 + tid) * 8;  // 1280*512
    int f = idx8 >> 9, rr = idx8 & 511;
    int lane = rr >> 3;
    int gate = f % 5, t = f / 5;
    int grp = t & 15, kc = t >> 4;
    int k0 = kc * 32 + ((lane >> 4) << 3);
    int n = gate * 256 + (grp << 4) + (lane & 15);
    const float* src = (k0 < 256) ? (Wl + n * 256 + k0) : (Wr + n * 256 + (k0 - 256));
    *(bf16x8*)(Wcf + idx8) = c8(src);
  } else {
    int g = b - (NB_LEAF + NB_WCF);  // 0..4
    __shared__ float er[300];
    for (int k = tid; k < 300; k += 256) er[k] = emb_last[k];
    __syncthreads();
    const int map[5] = {0, 1, 2, 2, 3};
    int wrow = map[g] * 256 + tid;
    const float* w = Wx + wrow * 300;
    float s = bx[wrow];
    for (int k = 0; k < 300; k++) s += er[k] * w[k];
    bias5[g * 256 + tid] = s;
  }
}

// ---- Compose RT=2 (B=4096 only): 1-D grid(512), row-affine slices ----
__global__ __launch_bounds__(256) void k_compose_rt2(
    const unsigned short* __restrict__ hprev, const float* __restrict__ cprev,
    const unsigned short* __restrict__ Wcf, const float* __restrict__ bias5,
    float* __restrict__ cO, unsigned short* __restrict__ hO, int B) {
  int bid = blockIdx.x;
  int slice = bid & 7;
  int rest = bid >> 3;              // 0..63
  int rowblock = slice * 4 + (rest & 3);
  int grp = rest >> 2;              // 0..15
  int lane = threadIdx.x & 63;
  int wave = threadIdx.x >> 6;
  int tb = (rowblock * 4 + wave) * 2;
  int m = lane & 15, quad = lane >> 4;

  f32x4 acc[2][5];
  const unsigned short* ar[2];
#pragma unroll
  for (int rt = 0; rt < 2; rt++) {
    int ra = (tb + rt) * 16 + m;
    ar[rt] = hprev + ra * 512 + quad * 8;
#pragma unroll
    for (int g = 0; g < 5; g++) acc[rt][g] = (f32x4){0.f, 0.f, 0.f, 0.f};
  }

#pragma unroll
  for (int kc = 0; kc < 16; kc++) {
    const unsigned short* bp = Wcf + ((kc * 16 + grp) * 5) * 512 + lane * 8;
    bf16x8 b0 = *(const bf16x8*)(bp);
    bf16x8 b1 = *(const bf16x8*)(bp + 512);
    bf16x8 b2 = *(const bf16x8*)(bp + 1024);
    bf16x8 b3 = *(const bf16x8*)(bp + 1536);
    bf16x8 b4 = *(const bf16x8*)(bp + 2048);
#pragma unroll
    for (int rt = 0; rt < 2; rt++) {
      bf16x8 a = *(const bf16x8*)(ar[rt] + kc * 32);
      acc[rt][0] = __builtin_amdgcn_mfma_f32_16x16x32_bf16(a, b0, acc[rt][0], 0, 0, 0);
      acc[rt][1] = __builtin_amdgcn_mfma_f32_16x16x32_bf16(a, b1, acc[rt][1], 0, 0, 0);
      acc[rt][2] = __builtin_amdgcn_mfma_f32_16x16x32_bf16(a, b2, acc[rt][2], 0, 0, 0);
      acc[rt][3] = __builtin_amdgcn_mfma_f32_16x16x32_bf16(a, b3, acc[rt][3], 0, 0, 0);
      acc[rt][4] = __builtin_amdgcn_mfma_f32_16x16x32_bf16(a, b4, acc[rt][4], 0, 0, 0);
    }
  }
  int col = grp * 16 + m;
  float b0 = bias5[col], b1 = bias5[256 + col], b2 = bias5[512 + col];
  float b3 = bias5[768 + col], b4 = bias5[1024 + col];
#pragma unroll
  for (int rt = 0; rt < 2; rt++) {
#pragma unroll
    for (int reg = 0; reg < 4; reg++) {
      int row = (tb + rt) * 16 + quad * 4 + reg;
      float u = tanhf(acc[rt][0][reg] + b0);
      float ig = sigf(acc[rt][1][reg] + b1);
      float lf = sigf(acc[rt][2][reg] + b2);
      float rf = sigf(acc[rt][3][reg] + b3);
      float o = sigf(acc[rt][4][reg] + b4);
      float lc = cprev[(2 * row) * MEM + col];
      float rc = cprev[(2 * row + 1) * MEM + col];
      float c = ig * u + lf * lc + rf * rc;
      cO[row * MEM + col] = c;
      hO[row * MEM + col] = f2b(o * tanhf(c));
    }
  }
}

// ---- K-split compose (B<=2048): grid(ceil(tiles/2),16) ----
// Block = (tile-pair tp, grp); wave w covers kc in [4w,4w+4); LDS reduce.
__global__ __launch_bounds__(256, 4) void k_compose_ksplit(
    const unsigned short* __restrict__ hprev, const float* __restrict__ cprev,
    const unsigned short* __restrict__ Wcf, const float* __restrict__ bias5,
    float* __restrict__ cO, unsigned short* __restrict__ hO,
    float* __restrict__ hOf, int B) {
  __shared__ __align__(16) float lds[4 * 2 * 5 * 64 * 4];  // 40KB
  int tid = threadIdx.x;
  int lane = tid & 63, wave = tid >> 6;
  int grp = blockIdx.y;
  int tp = blockIdx.x;
  int m = lane & 15, quad = lane >> 4;
  int tiles = (B + 15) >> 4;
  const bf16x8 zz = {0, 0, 0, 0, 0, 0, 0, 0};

  f32x4 acc[2][5];
  bool act[2], ok[2];
  bf16x8 av[2][4];  // A prefetched: [tile][kcl]
#pragma unroll
  for (int t = 0; t < 2; t++) {
    int gt = 2 * tp + t;
    act[t] = (gt < tiles);
    int ra = gt * 16 + m;
    ok[t] = act[t] && (ra < B);
    const unsigned short* ar = hprev + (size_t)ra * 512 + quad * 8;
#pragma unroll
    for (int kcl = 0; kcl < 4; kcl++)
      av[t][kcl] = ok[t] ? *(const bf16x8*)(ar + (wave * 4 + kcl) * 32) : zz;
#pragma unroll
    for (int q = 0; q < 5; q++) acc[t][q] = (f32x4){0.f, 0.f, 0.f, 0.f};
  }

#pragma unroll
  for (int kcl = 0; kcl < 4; kcl++) {
    int kc = wave * 4 + kcl;
    const unsigned short* bp = Wcf + ((kc * 16 + grp) * 5) * 512 + lane * 8;
    bf16x8 b0 = *(const bf16x8*)(bp);
    bf16x8 b1 = *(const bf16x8*)(bp + 512);
    bf16x8 b2 = *(const bf16x8*)(bp + 1024);
    bf16x8 b3 = *(const bf16x8*)(bp + 1536);
    bf16x8 b4 = *(const bf16x8*)(bp + 2048);
#pragma unroll
    for (int t = 0; t < 2; t++) {
      if (act[t]) {
        acc[t][0] = __builtin_amdgcn_mfma_f32_16x16x32_bf16(av[t][kcl], b0, acc[t][0], 0, 0, 0);
        acc[t][1] = __builtin_amdgcn_mfma_f32_16x16x32_bf16(av[t][kcl], b1, acc[t][1], 0, 0, 0);
        acc[t][2] = __builtin_amdgcn_mfma_f32_16x16x32_bf16(av[t][kcl], b2, acc[t][2], 0, 0, 0);
        acc[t][3] = __builtin_amdgcn_mfma_f32_16x16x32_bf16(av[t][kcl], b3, acc[t][3], 0, 0, 0);
        acc[t][4] = __builtin_amdgcn_mfma_f32_16x16x32_bf16(av[t][kcl], b4, acc[t][4], 0, 0, 0);
      }
    }
  }
#pragma unroll
  for (int t = 0; t < 2; t++)
    if (act[t])
#pragma unroll
      for (int q = 0; q < 5; q++)
        *(f32x4*)&lds[(((wave * 2 + t) * 5 + q) * 64 + lane) * 4] = acc[t][q];
  __syncthreads();

  if (wave < 2 && act[wave]) {
    int t = wave;
    int gt = 2 * tp + t;
    int col = grp * 16 + m;
    float b0 = bias5[col], b1 = bias5[256 + col], b2 = bias5[512 + col];
    float b3 = bias5[768 + col], b4 = bias5[1024 + col];
    f32x4 s[5];
#pragma unroll
    for (int q = 0; q < 5; q++) {
      s[q] = *(const f32x4*)&lds[(((0 * 2 + t) * 5 + q) * 64 + lane) * 4];
#pragma unroll
      for (int v = 1; v < 4; v++) {
        f32x4 p = *(const f32x4*)&lds[(((v * 2 + t) * 5 + q) * 64 + lane) * 4];
        s[q][0] += p[0]; s[q][1] += p[1]; s[q][2] += p[2]; s[q][3] += p[3];
      }
    }
#pragma unroll
    for (int reg = 0; reg < 4; reg++) {
      int row = gt * 16 + quad * 4 + reg;
      if (row >= B) continue;
      float u = tanhf(s[0][reg] + b0);
      float ig = sigf(s[1][reg] + b1);
      float lf = sigf(s[2][reg] + b2);
      float rf = sigf(s[3][reg] + b3);
      float o = sigf(s[4][reg] + b4);
      float lc = cprev[(2 * row) * MEM + col];
      float rc = cprev[(2 * row + 1) * MEM + col];
      float c = ig * u + lf * lc + rf * rc;
      float h = o * tanhf(c);
      cO[row * MEM + col] = c;
      hO[row * MEM + col] = f2b(h);
      if (hOf) hOf[row * MEM + col] = h;
    }
  }
}

extern "C" void kernel_launch(void* const* d_in, const int* in_sizes, int n_in,
                              void* d_out, int out_size, void* d_ws, size_t ws_size,
                              hipStream_t stream) {
  const float* embs = (const float*)d_in[0];
  const float* Wx = (const float*)d_in[1];
  const float* bx = (const float*)d_in[2];
  const float* Wl = (const float*)d_in[3];
  const float* Wr = (const float*)d_in[4];
  const float* emb_table = (const float*)d_in[5];
  float* out = (float*)d_out;

  // Workspace layout (~25 MB)
  float* ws = (float*)d_ws;
  float* cA = ws;                               // 8192*256 f32
  float* cB = cA + 8192 * 256;                  // 4096*256 f32
  float* bias5 = cB + 4096 * 256;               // 1280 f32
  unsigned short* hA = (unsigned short*)(bias5 + 1280);  // 8192*256 bf16
  unsigned short* hB = hA + 8192 * 256;                  // 4096*256 bf16
  unsigned short* Wcf = hB + 4096 * 256;                 // 1280*512
  unsigned short* Wxf = Wcf + 1280 * 512;                // 480*512
  unsigned short* eb = Wxf + 480 * 512;                  // 8192*320

  // 1) Prep1: eb + Wxf (1400 blocks)
  k_prep1<<<NB_EB + NB_WXF, 256, 0, stream>>>(embs, Wx, eb, Wxf);

  // 2) Leaf (+ Wcf shuffle + bias5 overlapped) -> cA, hA (8192 rows)
  k_leaf_fused<<<NB_LEAF + NB_WCF + 5, 256, 0, stream>>>(
      eb, Wxf, bx, Wx, Wl, Wr, emb_table + (in_sizes[5] - 300),
      Wcf, bias5, cA, hA);

  // 3) B=4096: RT=2 row-affine compose: (hA,cA) -> (cB,hB)
  k_compose_rt2<<<512, 256, 0, stream>>>(hA, cA, Wcf, bias5, cB, hB, 4096);

  // 4) B=2048..1: generalized K-split compose
  const float* cs = cB;
  const unsigned short* hs = hB;
  int B = 2048;
  int lvl = 1;
  while (B >= 1) {
    float* dc;
    unsigned short* dh;
    float* dhf = nullptr;
    if (B == 1) {
      dc = out;
      dh = hA;  // dummy bf16 sink
      dhf = out + 256;
    } else if ((lvl & 1) == 0) {
      dc = cB; dh = hB;
    } else {
      dc = cA; dh = hA;
    }
    int tiles = (B + 15) / 16;
    int gx = (tiles + 1) / 2;
    k_compose_ksplit<<<dim3(gx, 16), 256, 0, stream>>>(
        hs, cs, Wcf, bias5, dc, dh, dhf, B);
    cs = dc;
    hs = dh;
    B >>= 1;
    lvl++;
  }
}